// Round 7
// baseline (206.094 us; speedup 1.0000x reference)
//
#include <hip/hip_runtime.h>
#include <hip/hip_bf16.h>

// GraphormerAttention on MI355X — Round 7 (= R6 resubmit; broker timed out).
// R5 (174.5 us total; attn 52.6 us @ MfmaUtil 19.4 / VALUBusy 34.8): VALU census
// shows P-packing (~340 ops/tile) dominates the softmax path; both pipes <35%
// -> latency-bound at 2 blocks/CU. Changes, all numerics-identical:
//  * splitbf via native __float2bfloat16 (RNE, same as manual) -> v_cvt_pk pairs
//  * T14 reg-prefetch of next K/V/bins tile (attn) and next A/B tile (qkv, wo)
//  * T5 s_setprio(1) around MFMA clusters
//  * bins/conv_x/prep_w fused into one prep_all launch (saves 2 gaps)

#define NTOK   2048
#define DM     512
#define NH     8
#define DH     64
#define NBINS  16
#define NSPLIT 4
#define KPS    (NTOK / NSPLIT)   // 512 keys per split

typedef float  f32x16 __attribute__((ext_vector_type(16)));
typedef short  short8 __attribute__((ext_vector_type(8)));
typedef unsigned short ushort_t;

#define MFMA32(A, B, C) __builtin_amdgcn_mfma_f32_32x32x16_bf16((A), (B), (C), 0, 0, 0)

__device__ __forceinline__ ushort_t f2bf(float x) {   // fp32 -> bf16 RNE (native cvt)
    __hip_bfloat16 h = __float2bfloat16(x);
    union { __hip_bfloat16 b; ushort_t u; } v; v.b = h;
    return v.u;
}
__device__ __forceinline__ float bf2f(ushort_t b) {
    union { unsigned u; float f; } v; v.u = ((unsigned)b) << 16;
    return v.f;
}
__device__ __forceinline__ void splitbf(float x, ushort_t& hi, ushort_t& lo) {
    hi = f2bf(x);
    lo = f2bf(x - bf2f(hi));
}

union FragU { unsigned u[4]; short8 s; };

// ---------------------------------------------------------------- prep ----
__device__ __forceinline__ int z_to_bin(float z) {
    int b = (int)floorf(z / 5.0f * 16.0f);   // match jnp op order
    return b < 0 ? 0 : (b > 15 ? 15 : b);
}

// Fused: bins (blocks 0..4095), conv_x (4096..5119), prep_w (5120..6143).
__global__ __launch_bounds__(256)
void prep_all(const float* __restrict__ z, unsigned char* __restrict__ bins,
              const float* __restrict__ x, ushort_t* __restrict__ xh, ushort_t* __restrict__ xl,
              const float* __restrict__ Wq, const float* __restrict__ Wk,
              const float* __restrict__ Wv, const float* __restrict__ Wo,
              ushort_t* __restrict__ wt_hi_base, ushort_t* __restrict__ wt_lo_base) {
    const int bid = blockIdx.x;
    const int t   = threadIdx.x;
    __shared__ float Tl[32][33];

    if (bid < 4096) {                       // ---- bins
        int i = (bid * 256 + t) * 4;
        float4 zv = *reinterpret_cast<const float4*>(z + i);
        uchar4 b;
        b.x = (unsigned char)z_to_bin(zv.x);
        b.y = (unsigned char)z_to_bin(zv.y);
        b.z = (unsigned char)z_to_bin(zv.z);
        b.w = (unsigned char)z_to_bin(zv.w);
        *reinterpret_cast<uchar4*>(bins + i) = b;
    } else if (bid < 5120) {                // ---- conv_x
        int i = ((bid - 4096) * 256 + t) * 4;
        float4 v = *reinterpret_cast<const float4*>(x + i);
        ushort_t h[4], l[4];
        splitbf(v.x, h[0], l[0]); splitbf(v.y, h[1], l[1]);
        splitbf(v.z, h[2], l[2]); splitbf(v.w, h[3], l[3]);
        *reinterpret_cast<ushort4*>(xh + i) = make_ushort4(h[0], h[1], h[2], h[3]);
        *reinterpret_cast<ushort4*>(xl + i) = make_ushort4(l[0], l[1], l[2], l[3]);
    } else {                                // ---- prep_w (transpose-convert)
        const int pz  = bid - 5120;
        const int zz  = pz >> 8;
        const int rem = pz & 255;
        const float* __restrict__ W = zz == 0 ? Wq : zz == 1 ? Wk : zz == 2 ? Wv : Wo;
        ushort_t* __restrict__ th = wt_hi_base + (size_t)zz * DM * DM * 2;
        ushort_t* __restrict__ tl = wt_lo_base + (size_t)zz * DM * DM * 2;
        const int r0 = (rem >> 4) * 32;     // k rows
        const int c0 = (rem & 15) * 32;     // n cols
        {
            const int r = t >> 3, c4 = (t & 7) * 4;
            float4 v = *reinterpret_cast<const float4*>(W + (size_t)(r0 + r) * DM + c0 + c4);
            Tl[r][c4 + 0] = v.x; Tl[r][c4 + 1] = v.y; Tl[r][c4 + 2] = v.z; Tl[r][c4 + 3] = v.w;
        }
        __syncthreads();
        {
            const int c = t >> 3, r4 = (t & 7) * 4;
            ushort_t h4[4], l4[4];
            #pragma unroll
            for (int k = 0; k < 4; ++k) splitbf(Tl[r4 + k][c], h4[k], l4[k]);
            *reinterpret_cast<ushort4*>(th + (size_t)(c0 + c) * DM + r0 + r4) =
                make_ushort4(h4[0], h4[1], h4[2], h4[3]);
            *reinterpret_cast<ushort4*>(tl + (size_t)(c0 + c) * DM + r0 + r4) =
                make_ushort4(l4[0], l4[1], l4[2], l4[3]);
        }
    }
}

// ----------------------------------------------------------- QKV GEMM ----
// C[2048,512] = x @ W + b via split-bf16 MFMA. Block 64x64, BK=32, 4 waves
// (2x2 of 32x32). z picks Q/K/V. Q,K out: [h][tok][d] hi/lo. V out: [h][d][tok].
__global__ __launch_bounds__(256, 3)
void qkv_gemm_mfma(const ushort_t* __restrict__ x_hi, const ushort_t* __restrict__ x_lo,
                   const ushort_t* __restrict__ wqt_hi, const ushort_t* __restrict__ wqt_lo,
                   const ushort_t* __restrict__ wkt_hi, const ushort_t* __restrict__ wkt_lo,
                   const ushort_t* __restrict__ wvt_hi, const ushort_t* __restrict__ wvt_lo,
                   const float* __restrict__ bq, const float* __restrict__ bk,
                   const float* __restrict__ bv,
                   ushort_t* __restrict__ q_hi, ushort_t* __restrict__ q_lo,
                   ushort_t* __restrict__ k_hi, ushort_t* __restrict__ k_lo,
                   ushort_t* __restrict__ vT_hi, ushort_t* __restrict__ vT_lo) {
    const int z = blockIdx.z;
    const ushort_t* __restrict__ bt_hi = z == 0 ? wqt_hi : z == 1 ? wkt_hi : wvt_hi;
    const ushort_t* __restrict__ bt_lo = z == 0 ? wqt_lo : z == 1 ? wkt_lo : wvt_lo;
    const float*    __restrict__ bias  = z == 0 ? bq : z == 1 ? bk : bv;

    const int n0 = blockIdx.x * 64;
    const int m0 = blockIdx.y * 64;
    const int t  = threadIdx.x;
    const int wid = t >> 6, l = t & 63, hf = l >> 5, lq = l & 31;
    const int wm = wid >> 1, wn = wid & 1;

    __shared__ __align__(16) ushort_t Ash_hi[64 * 40], Ash_lo[64 * 40];
    __shared__ __align__(16) ushort_t Bsh_hi[64 * 40], Bsh_lo[64 * 40];

    f32x16 acc;
    #pragma unroll
    for (int i = 0; i < 16; ++i) acc[i] = 0.0f;

    const int sr = t >> 2, sc = t & 3;   // staging: 64 rows x 4 chunks of 16B

    // T14 reg-prefetch
    uint4 ra_h, ra_l, rb_h, rb_l;
    auto LOAD = [&](int k0) {
        ra_h = *reinterpret_cast<const uint4*>(&x_hi[(size_t)(m0 + sr) * DM + k0 + 8 * sc]);
        ra_l = *reinterpret_cast<const uint4*>(&x_lo[(size_t)(m0 + sr) * DM + k0 + 8 * sc]);
        rb_h = *reinterpret_cast<const uint4*>(&bt_hi[(size_t)(n0 + sr) * DM + k0 + 8 * sc]);
        rb_l = *reinterpret_cast<const uint4*>(&bt_lo[(size_t)(n0 + sr) * DM + k0 + 8 * sc]);
    };
    LOAD(0);

    for (int k0 = 0; k0 < DM; k0 += 32) {
        __syncthreads();   // prior compute done reading LDS (WAR)
        *reinterpret_cast<uint4*>(&Ash_hi[sr * 40 + 8 * sc]) = ra_h;
        *reinterpret_cast<uint4*>(&Ash_lo[sr * 40 + 8 * sc]) = ra_l;
        *reinterpret_cast<uint4*>(&Bsh_hi[sr * 40 + 8 * sc]) = rb_h;
        *reinterpret_cast<uint4*>(&Bsh_lo[sr * 40 + 8 * sc]) = rb_l;
        __syncthreads();
        if (k0 + 32 < DM) LOAD(k0 + 32);   // prefetch next tile under compute

        __builtin_amdgcn_s_setprio(1);
        #pragma unroll
        for (int kp = 0; kp < 2; ++kp) {
            const int co = 8 * (hf + 2 * kp);
            short8 ah = *reinterpret_cast<const short8*>(&Ash_hi[(32 * wm + lq) * 40 + co]);
            short8 al = *reinterpret_cast<const short8*>(&Ash_lo[(32 * wm + lq) * 40 + co]);
            short8 bh = *reinterpret_cast<const short8*>(&Bsh_hi[(32 * wn + lq) * 40 + co]);
            short8 bl = *reinterpret_cast<const short8*>(&Bsh_lo[(32 * wn + lq) * 40 + co]);
            acc = MFMA32(ah, bh, acc);
            acc = MFMA32(ah, bl, acc);
            acc = MFMA32(al, bh, acc);
        }
        __builtin_amdgcn_s_setprio(0);
    }

    const int nl = lq + 32 * wn;
    const float bval = bias[n0 + nl];
    const int hh = n0 >> 6;

    #pragma unroll
    for (int r = 0; r < 16; ++r) {
        const int ml = (r & 3) + 8 * (r >> 2) + 4 * hf + 32 * wm;
        const float v = acc[r] + bval;
        ushort_t hi, lo; splitbf(v, hi, lo);
        if (z < 2) {
            ushort_t* dh = z == 0 ? q_hi : k_hi;
            ushort_t* dl = z == 0 ? q_lo : k_lo;
            const size_t o = ((size_t)hh * NTOK + m0 + ml) * DH + nl;
            dh[o] = hi; dl[o] = lo;
        } else {
            const size_t o = ((size_t)hh * DH + nl) * NTOK + m0 + ml;
            vT_hi[o] = hi; vT_lo[o] = lo;
        }
    }
}

// ------------------------------------------------------------ Wo GEMM ----
__global__ __launch_bounds__(256, 3)
void wo_gemm_mfma(const ushort_t* __restrict__ a_hi, const ushort_t* __restrict__ a_lo,
                  const ushort_t* __restrict__ bt_hi, const ushort_t* __restrict__ bt_lo,
                  const float* __restrict__ bias, float* __restrict__ out) {
    const int n0 = blockIdx.x * 64;
    const int m0 = blockIdx.y * 64;
    const int t  = threadIdx.x;
    const int wid = t >> 6, l = t & 63, hf = l >> 5, lq = l & 31;
    const int wm = wid >> 1, wn = wid & 1;

    __shared__ __align__(16) ushort_t Ash_hi[64 * 40], Ash_lo[64 * 40];
    __shared__ __align__(16) ushort_t Bsh_hi[64 * 40], Bsh_lo[64 * 40];

    f32x16 acc;
    #pragma unroll
    for (int i = 0; i < 16; ++i) acc[i] = 0.0f;

    const int sr = t >> 2, sc = t & 3;

    uint4 ra_h, ra_l, rb_h, rb_l;
    auto LOAD = [&](int k0) {
        ra_h = *reinterpret_cast<const uint4*>(&a_hi[(size_t)(m0 + sr) * DM + k0 + 8 * sc]);
        ra_l = *reinterpret_cast<const uint4*>(&a_lo[(size_t)(m0 + sr) * DM + k0 + 8 * sc]);
        rb_h = *reinterpret_cast<const uint4*>(&bt_hi[(size_t)(n0 + sr) * DM + k0 + 8 * sc]);
        rb_l = *reinterpret_cast<const uint4*>(&bt_lo[(size_t)(n0 + sr) * DM + k0 + 8 * sc]);
    };
    LOAD(0);

    for (int k0 = 0; k0 < DM; k0 += 32) {
        __syncthreads();
        *reinterpret_cast<uint4*>(&Ash_hi[sr * 40 + 8 * sc]) = ra_h;
        *reinterpret_cast<uint4*>(&Ash_lo[sr * 40 + 8 * sc]) = ra_l;
        *reinterpret_cast<uint4*>(&Bsh_hi[sr * 40 + 8 * sc]) = rb_h;
        *reinterpret_cast<uint4*>(&Bsh_lo[sr * 40 + 8 * sc]) = rb_l;
        __syncthreads();
        if (k0 + 32 < DM) LOAD(k0 + 32);

        __builtin_amdgcn_s_setprio(1);
        #pragma unroll
        for (int kp = 0; kp < 2; ++kp) {
            const int co = 8 * (hf + 2 * kp);
            short8 ah = *reinterpret_cast<const short8*>(&Ash_hi[(32 * wm + lq) * 40 + co]);
            short8 al = *reinterpret_cast<const short8*>(&Ash_lo[(32 * wm + lq) * 40 + co]);
            short8 bh = *reinterpret_cast<const short8*>(&Bsh_hi[(32 * wn + lq) * 40 + co]);
            short8 bl = *reinterpret_cast<const short8*>(&Bsh_lo[(32 * wn + lq) * 40 + co]);
            acc = MFMA32(ah, bh, acc);
            acc = MFMA32(ah, bl, acc);
            acc = MFMA32(al, bh, acc);
        }
        __builtin_amdgcn_s_setprio(0);
    }

    const int nl = lq + 32 * wn;
    const float bval = bias[n0 + nl];
    #pragma unroll
    for (int r = 0; r < 16; ++r) {
        const int ml = (r & 3) + 8 * (r >> 2) + 4 * hf + 32 * wm;
        out[(size_t)(m0 + ml) * DM + n0 + nl] = acc[r] + bval;
    }
}

// ----------------------------------------------------------- attention ----
// grid (16 qtiles, 8 heads, NSPLIT). QT=128 (4 waves x 32-q strips), KT=64.
// S^T = K·Q^T so each lane owns one q-row: in-register softmax. P split to
// bf16 hi/lo in-register; lane^32 exchange builds PV A-frags.
// Loop: [bar] regs->LDS [bar] prefetch(t+1)->regs; compute(t).
__global__ __launch_bounds__(256, 2)
void attn_mfma(const ushort_t* __restrict__ q_hi, const ushort_t* __restrict__ q_lo,
               const ushort_t* __restrict__ k_hi, const ushort_t* __restrict__ k_lo,
               const ushort_t* __restrict__ vT_hi, const ushort_t* __restrict__ vT_lo,
               const unsigned char* __restrict__ bins_g, const float* __restrict__ z_table,
               float* __restrict__ po, float* __restrict__ pm, float* __restrict__ pl) {
    const int hd = blockIdx.y;
    const int q0 = blockIdx.x * 128;
    const int zs = blockIdx.z;
    const int t  = threadIdx.x;
    const int wid = t >> 6, l = t & 63, hf = l >> 5, lq = l & 31;
    const int qs = q0 + 32 * wid;

    __shared__ __align__(16) ushort_t Ksh_hi[64 * 72], Ksh_lo[64 * 72];
    __shared__ __align__(16) ushort_t Vsh_hi[64 * 72], Vsh_lo[64 * 72];
    __shared__ __align__(16) unsigned char Bsh[128 * 80];

    const float ztab = z_table[(l & 15) * NH + hd];

    // Q B-frags in registers
    short8 qf_hi[4], qf_lo[4];
    #pragma unroll
    for (int kp = 0; kp < 4; ++kp) {
        const size_t o = ((size_t)hd * NTOK + qs + lq) * DH + 8 * hf + 16 * kp;
        qf_hi[kp] = *reinterpret_cast<const short8*>(&q_hi[o]);
        qf_lo[kp] = *reinterpret_cast<const short8*>(&q_lo[o]);
    }

    float m_run = -1e30f, l_run = 0.0f;
    f32x16 oacc0, oacc1;
    #pragma unroll
    for (int i = 0; i < 16; ++i) { oacc0[i] = 0.0f; oacc1[i] = 0.0f; }

    const float scale = 0.125f;
    const int kbase = zs * KPS;

    // staging address components (functions of t only)
    const int strow = t >> 3, stcol = (t & 7) * 8;          // K/V: 2 halves of 64 rows
    const int bqr = t >> 2, bcol = (t & 3) * 16;            // bins: 2 halves of 128 rows

    // T14 prefetch registers: K/V hi/lo x 2 chunks + bins x 2
    uint4 rKh[2], rKl[2], rVh[2], rVl[2], rB[2];
    auto LOADT = [&](int ktb) {
        #pragma unroll
        for (int i = 0; i < 2; ++i) {
            const int r = strow + 32 * i;
            const size_t kg = ((size_t)hd * NTOK + ktb + r) * DH + stcol;
            const size_t vg = ((size_t)hd * DH + r) * NTOK + ktb + stcol;
            rKh[i] = *reinterpret_cast<const uint4*>(&k_hi[kg]);
            rKl[i] = *reinterpret_cast<const uint4*>(&k_lo[kg]);
            rVh[i] = *reinterpret_cast<const uint4*>(&vT_hi[vg]);
            rVl[i] = *reinterpret_cast<const uint4*>(&vT_lo[vg]);
        }
        #pragma unroll
        for (int i = 0; i < 2; ++i) {
            const int qr = bqr + 64 * i;
            rB[i] = *reinterpret_cast<const uint4*>(&bins_g[(size_t)(q0 + qr) * NTOK + ktb + bcol]);
        }
    };
    LOADT(kbase);

    const int NT = KPS / 64;
    for (int kt8 = 0; kt8 < NT; ++kt8) {
        __syncthreads();   // prior compute done reading LDS (WAR)
        #pragma unroll
        for (int i = 0; i < 2; ++i) {
            const int r = strow + 32 * i;
            *reinterpret_cast<uint4*>(&Ksh_hi[r * 72 + stcol]) = rKh[i];
            *reinterpret_cast<uint4*>(&Ksh_lo[r * 72 + stcol]) = rKl[i];
            *reinterpret_cast<uint4*>(&Vsh_hi[r * 72 + stcol]) = rVh[i];
            *reinterpret_cast<uint4*>(&Vsh_lo[r * 72 + stcol]) = rVl[i];
        }
        #pragma unroll
        for (int i = 0; i < 2; ++i) {
            const int qr = bqr + 64 * i;
            *reinterpret_cast<uint4*>(&Bsh[qr * 80 + bcol]) = rB[i];
        }
        __syncthreads();
        if (kt8 + 1 < NT) LOADT(kbase + (kt8 + 1) * 64);   // hide HBM/L2 under compute

        // -- S^T = K · Q^T
        f32x16 sacc0, sacc1;
        #pragma unroll
        for (int i = 0; i < 16; ++i) { sacc0[i] = 0.0f; sacc1[i] = 0.0f; }
        __builtin_amdgcn_s_setprio(1);
        #pragma unroll
        for (int kp = 0; kp < 4; ++kp) {
            const int co = 8 * (hf + 2 * kp);
            short8 k0h = *reinterpret_cast<const short8*>(&Ksh_hi[lq * 72 + co]);
            short8 k0l = *reinterpret_cast<const short8*>(&Ksh_lo[lq * 72 + co]);
            short8 k1h = *reinterpret_cast<const short8*>(&Ksh_hi[(lq + 32) * 72 + co]);
            short8 k1l = *reinterpret_cast<const short8*>(&Ksh_lo[(lq + 32) * 72 + co]);
            sacc0 = MFMA32(k0h, qf_hi[kp], sacc0);
            sacc0 = MFMA32(k0h, qf_lo[kp], sacc0);
            sacc0 = MFMA32(k0l, qf_hi[kp], sacc0);
            sacc1 = MFMA32(k1h, qf_hi[kp], sacc1);
            sacc1 = MFMA32(k1h, qf_lo[kp], sacc1);
            sacc1 = MFMA32(k1l, qf_hi[kp], sacc1);
        }
        __builtin_amdgcn_s_setprio(0);

        // -- scale + z-bias
        float sv[2][16];
        #pragma unroll
        for (int t2 = 0; t2 < 2; ++t2) {
            #pragma unroll
            for (int b = 0; b < 4; ++b) {
                const unsigned bw = *reinterpret_cast<const unsigned*>(
                    &Bsh[(32 * wid + lq) * 80 + 4 * (hf + 2 * b + 8 * t2)]);
                #pragma unroll
                for (int c = 0; c < 4; ++c) {
                    const int r = c + 4 * b;
                    const int src = (int)((bw >> (8 * c)) & 0xFF) | (l & 48);
                    const float bias = __shfl(ztab, src, 64);
                    const float sraw = (t2 == 0 ? sacc0[r] : sacc1[r]);
                    sv[t2][r] = sraw * scale + bias;
                }
            }
        }

        // -- online softmax (row spread across lane pair l, l^32)
        float tm = sv[0][0];
        #pragma unroll
        for (int t2 = 0; t2 < 2; ++t2)
            #pragma unroll
            for (int r = 0; r < 16; ++r) tm = fmaxf(tm, sv[t2][r]);
        tm = fmaxf(tm, __shfl_xor(tm, 32, 64));
        const float mn = fmaxf(m_run, tm);
        const float ef = __expf(m_run - mn);
        m_run = mn;

        float pv[2][16];
        float ts = 0.0f;
        #pragma unroll
        for (int t2 = 0; t2 < 2; ++t2)
            #pragma unroll
            for (int r = 0; r < 16; ++r) {
                const float p = __expf(sv[t2][r] - mn);
                pv[t2][r] = p;
                ts += p;
            }
        ts += __shfl_xor(ts, 32, 64);
        l_run = l_run * ef + ts;

        // -- rescale O accumulators
        #pragma unroll
        for (int r = 0; r < 16; ++r) {
            const int qloc = (r & 3) + 8 * (r >> 2) + 4 * hf;
            const float efr = __shfl(ef, qloc | (l & 32), 64);
            oacc0[r] *= efr;
            oacc1[r] *= efr;
        }

        // -- pack P to bf16 hi/lo (native cvt) and build PV A-frags
        unsigned phi[2][8], plo[2][8];
        #pragma unroll
        for (int t2 = 0; t2 < 2; ++t2)
            #pragma unroll
            for (int i = 0; i < 8; ++i) {
                ushort_t ha, la, hb, lb;
                splitbf(pv[t2][2 * i],     ha, la);
                splitbf(pv[t2][2 * i + 1], hb, lb);
                phi[t2][i] = (unsigned)ha | ((unsigned)hb << 16);
                plo[t2][i] = (unsigned)la | ((unsigned)lb << 16);
            }

        FragU paf_hi[2][2], paf_lo[2][2];
        #pragma unroll
        for (int t2 = 0; t2 < 2; ++t2)
            #pragma unroll
            for (int e = 0; e < 2; ++e) {
                {
                    const unsigned pA0 = phi[t2][4 * e], pA1 = phi[t2][4 * e + 1];
                    const unsigned pB0 = phi[t2][4 * e + 2], pB1 = phi[t2][4 * e + 3];
                    const unsigned s0 = hf ? pA0 : pB0, s1 = hf ? pA1 : pB1;
                    const unsigned r0 = (unsigned)__shfl_xor((int)s0, 32, 64);
                    const unsigned r1 = (unsigned)__shfl_xor((int)s1, 32, 64);
                    paf_hi[t2][e].u[0] = hf ? r0 : pA0;
                    paf_hi[t2][e].u[1] = hf ? r1 : pA1;
                    paf_hi[t2][e].u[2] = hf ? pB0 : r0;
                    paf_hi[t2][e].u[3] = hf ? pB1 : r1;
                }
                {
                    const unsigned pA0 = plo[t2][4 * e], pA1 = plo[t2][4 * e + 1];
                    const unsigned pB0 = plo[t2][4 * e + 2], pB1 = plo[t2][4 * e + 3];
                    const unsigned s0 = hf ? pA0 : pB0, s1 = hf ? pA1 : pB1;
                    const unsigned r0 = (unsigned)__shfl_xor((int)s0, 32, 64);
                    const unsigned r1 = (unsigned)__shfl_xor((int)s1, 32, 64);
                    paf_lo[t2][e].u[0] = hf ? r0 : pA0;
                    paf_lo[t2][e].u[1] = hf ? r1 : pA1;
                    paf_lo[t2][e].u[2] = hf ? pB0 : r0;
                    paf_lo[t2][e].u[3] = hf ? pB1 : r1;
                }
            }

        // -- O += P · V
        __builtin_amdgcn_s_setprio(1);
        #pragma unroll
        for (int kp = 0; kp < 4; ++kp) {
            const int t2 = kp >> 1, e = kp & 1;
            const int co = 8 * (hf + 2 * kp);
            short8 v0h = *reinterpret_cast<const short8*>(&Vsh_hi[lq * 72 + co]);
            short8 v0l = *reinterpret_cast<const short8*>(&Vsh_lo[lq * 72 + co]);
            oacc0 = MFMA32(paf_hi[t2][e].s, v0h, oacc0);
            oacc0 = MFMA32(paf_hi[t2][e].s, v0l, oacc0);
            oacc0 = MFMA32(paf_lo[t2][e].s, v0h, oacc0);
            short8 v1h = *reinterpret_cast<const short8*>(&Vsh_hi[(lq + 32) * 72 + co]);
            short8 v1l = *reinterpret_cast<const short8*>(&Vsh_lo[(lq + 32) * 72 + co]);
            oacc1 = MFMA32(paf_hi[t2][e].s, v1h, oacc1);
            oacc1 = MFMA32(paf_hi[t2][e].s, v1l, oacc1);
            oacc1 = MFMA32(paf_lo[t2][e].s, v1h, oacc1);
        }
        __builtin_amdgcn_s_setprio(0);
    }

    // -- epilogue: unnormalized partial O + (m, l)
    #pragma unroll
    for (int r = 0; r < 16; ++r) {
        const int qloc = (r & 3) + 8 * (r >> 2) + 4 * hf;
        const size_t row = ((size_t)(zs * NH + hd) * NTOK + qs + qloc) * DH;
        po[row + lq]      = oacc0[r];
        po[row + lq + 32] = oacc1[r];
    }
    if (hf == 0) {
        const size_t row = (size_t)(zs * NH + hd) * NTOK + qs + lq;
        pm[row] = m_run;
        pl[row] = l_run;
    }
}

// --------------------------------------------------------------- merge ----
__global__ __launch_bounds__(256)
void merge_kernel(const float* __restrict__ po, const float* __restrict__ pm,
                  const float* __restrict__ pl,
                  ushort_t* __restrict__ o_hi, ushort_t* __restrict__ o_lo) {
    const int idx = blockIdx.x * 256 + threadIdx.x;
    const int d4 = (idx & 15) * 4;
    const int q  = (idx >> 4) & (NTOK - 1);
    const int hh = idx >> 15;

    float ms[NSPLIT];
    float M = -1e30f;
    #pragma unroll
    for (int s = 0; s < NSPLIT; ++s) {
        ms[s] = pm[((size_t)s * NH + hh) * NTOK + q];
        M = fmaxf(M, ms[s]);
    }
    float L = 0.0f;
    float4 o = make_float4(0.f, 0.f, 0.f, 0.f);
    #pragma unroll
    for (int s = 0; s < NSPLIT; ++s) {
        const float w = __expf(ms[s] - M);
        L += w * pl[((size_t)s * NH + hh) * NTOK + q];
        float4 p = *reinterpret_cast<const float4*>(
            po + (((size_t)s * NH + hh) * NTOK + q) * DH + d4);
        o.x += w * p.x; o.y += w * p.y; o.z += w * p.z; o.w += w * p.w;
    }
    const float inv = 1.0f / L;
    o.x *= inv; o.y *= inv; o.z *= inv; o.w *= inv;

    ushort_t h4[4], l4[4];
    splitbf(o.x, h4[0], l4[0]); splitbf(o.y, h4[1], l4[1]);
    splitbf(o.z, h4[2], l4[2]); splitbf(o.w, h4[3], l4[3]);
    const size_t oo = (size_t)q * DM + hh * DH + d4;
    *reinterpret_cast<ushort4*>(o_hi + oo) = make_ushort4(h4[0], h4[1], h4[2], h4[3]);
    *reinterpret_cast<ushort4*>(o_lo + oo) = make_ushort4(l4[0], l4[1], l4[2], l4[3]);
}

// --------------------------------------------------------------- launch ----
extern "C" void kernel_launch(void* const* d_in, const int* in_sizes, int n_in,
                              void* d_out, int out_size, void* d_ws, size_t ws_size,
                              hipStream_t stream) {
    const float* x        = (const float*)d_in[0];
    const float* z_matrix = (const float*)d_in[1];
    const float* Wq       = (const float*)d_in[2];
    const float* bq       = (const float*)d_in[3];
    const float* Wk       = (const float*)d_in[4];
    const float* bk       = (const float*)d_in[5];
    const float* Wv       = (const float*)d_in[6];
    const float* bv       = (const float*)d_in[7];
    const float* Wo       = (const float*)d_in[8];
    const float* bo       = (const float*)d_in[9];
    const float* z_table  = (const float*)d_in[10];
    float* out            = (float*)d_out;

    // ---- workspace layout (40.5 MB) ----
    uint8_t* w = (uint8_t*)d_ws;
    const size_t MB = 1024 * 1024;
    ushort_t* x_hi  = (ushort_t*)(w + 0);
    ushort_t* x_lo  = (ushort_t*)(w + 2  * MB);
    ushort_t* wqt_hi= (ushort_t*)(w + 4  * MB);
    ushort_t* wqt_lo= (ushort_t*)(w + 4  * MB + 512 * 1024);
    ushort_t* wkt_hi= (ushort_t*)(w + 5  * MB);
    ushort_t* wkt_lo= (ushort_t*)(w + 5  * MB + 512 * 1024);
    ushort_t* wvt_hi= (ushort_t*)(w + 6  * MB);
    ushort_t* wvt_lo= (ushort_t*)(w + 6  * MB + 512 * 1024);
    ushort_t* wot_hi= (ushort_t*)(w + 7  * MB);
    ushort_t* wot_lo= (ushort_t*)(w + 7  * MB + 512 * 1024);
    ushort_t* q_hi  = (ushort_t*)(w + 8  * MB);
    ushort_t* q_lo  = (ushort_t*)(w + 10 * MB);
    ushort_t* k_hi  = (ushort_t*)(w + 12 * MB);
    ushort_t* k_lo  = (ushort_t*)(w + 14 * MB);
    ushort_t* vT_hi = (ushort_t*)(w + 16 * MB);
    ushort_t* vT_lo = (ushort_t*)(w + 18 * MB);
    unsigned char* bins = (unsigned char*)(w + 20 * MB);
    float* po = (float*)(w + 24 * MB);
    float* pm = (float*)(w + 40 * MB);
    float* pl = (float*)(w + 40 * MB + 256 * 1024);
    ushort_t* o_hi = x_hi;   // alias: x dead after qkv
    ushort_t* o_lo = x_lo;

    // 1) fused prep: bins + conv_x + prep_w
    prep_all<<<dim3(4096 + 1024 + 1024), dim3(256), 0, stream>>>(
        z_matrix, bins, x, x_hi, x_lo, Wq, Wk, Wv, Wo,
        (ushort_t*)(w + 4 * MB), (ushort_t*)(w + 4 * MB + 512 * 1024));

    // 2) QKV projection (z-fused, 768 blocks)
    qkv_gemm_mfma<<<dim3(DM / 64, NTOK / 64, 3), dim3(256), 0, stream>>>(
        x_hi, x_lo,
        wqt_hi, wqt_lo, wkt_hi, wkt_lo, wvt_hi, wvt_lo,
        bq, bk, bv,
        q_hi, q_lo, k_hi, k_lo, vT_hi, vT_lo);

    // 3) attention (512 blocks)
    attn_mfma<<<dim3(NTOK / 128, NH, NSPLIT), dim3(256), 0, stream>>>(
        q_hi, q_lo, k_hi, k_lo, vT_hi, vT_lo, bins, z_table, po, pm, pl);

    // 4) merge partials -> o hi/lo
    merge_kernel<<<dim3(NH * NTOK * DH / 4 / 256), dim3(256), 0, stream>>>(
        po, pm, pl, o_hi, o_lo);

    // 5) output projection
    wo_gemm_mfma<<<dim3(DM / 64, NTOK / 64), dim3(256), 0, stream>>>(
        o_hi, o_lo, wot_hi, wot_lo, bo, out);
}

// Round 11
// 164.559 us; speedup vs baseline: 1.2524x; 1.2524x over previous
//
#include <hip/hip_runtime.h>
#include <hip/hip_bf16.h>

// GraphormerAttention on MI355X — Round 11 (= R8/R9/R10 resubmit; broker timed out 3x).
// R7 post-mortem: T14 reg-prefetch in attn spilled to scratch (WRITE_SIZE
// 16.9->175 MB, attn 52.6->86.8 us). REVERTED attn staging to R5's direct
// global->LDS form. KEPT (no harm observed): native-cvt splitbf, setprio,
// fused prep, GEMM reg-prefetch (non-attn time 121.9->119.3 us).

#define NTOK   2048
#define DM     512
#define NH     8
#define DH     64
#define NBINS  16
#define NSPLIT 4
#define KPS    (NTOK / NSPLIT)   // 512 keys per split

typedef float  f32x16 __attribute__((ext_vector_type(16)));
typedef short  short8 __attribute__((ext_vector_type(8)));
typedef unsigned short ushort_t;

#define MFMA32(A, B, C) __builtin_amdgcn_mfma_f32_32x32x16_bf16((A), (B), (C), 0, 0, 0)

__device__ __forceinline__ ushort_t f2bf(float x) {   // fp32 -> bf16 RNE (native cvt)
    __hip_bfloat16 h = __float2bfloat16(x);
    union { __hip_bfloat16 b; ushort_t u; } v; v.b = h;
    return v.u;
}
__device__ __forceinline__ float bf2f(ushort_t b) {
    union { unsigned u; float f; } v; v.u = ((unsigned)b) << 16;
    return v.f;
}
__device__ __forceinline__ void splitbf(float x, ushort_t& hi, ushort_t& lo) {
    hi = f2bf(x);
    lo = f2bf(x - bf2f(hi));
}

union FragU { unsigned u[4]; short8 s; };

// ---------------------------------------------------------------- prep ----
__device__ __forceinline__ int z_to_bin(float z) {
    int b = (int)floorf(z / 5.0f * 16.0f);   // match jnp op order
    return b < 0 ? 0 : (b > 15 ? 15 : b);
}

// Fused: bins (blocks 0..4095), conv_x (4096..5119), prep_w (5120..6143).
__global__ __launch_bounds__(256)
void prep_all(const float* __restrict__ z, unsigned char* __restrict__ bins,
              const float* __restrict__ x, ushort_t* __restrict__ xh, ushort_t* __restrict__ xl,
              const float* __restrict__ Wq, const float* __restrict__ Wk,
              const float* __restrict__ Wv, const float* __restrict__ Wo,
              ushort_t* __restrict__ wt_hi_base, ushort_t* __restrict__ wt_lo_base) {
    const int bid = blockIdx.x;
    const int t   = threadIdx.x;
    __shared__ float Tl[32][33];

    if (bid < 4096) {                       // ---- bins
        int i = (bid * 256 + t) * 4;
        float4 zv = *reinterpret_cast<const float4*>(z + i);
        uchar4 b;
        b.x = (unsigned char)z_to_bin(zv.x);
        b.y = (unsigned char)z_to_bin(zv.y);
        b.z = (unsigned char)z_to_bin(zv.z);
        b.w = (unsigned char)z_to_bin(zv.w);
        *reinterpret_cast<uchar4*>(bins + i) = b;
    } else if (bid < 5120) {                // ---- conv_x
        int i = ((bid - 4096) * 256 + t) * 4;
        float4 v = *reinterpret_cast<const float4*>(x + i);
        ushort_t h[4], l[4];
        splitbf(v.x, h[0], l[0]); splitbf(v.y, h[1], l[1]);
        splitbf(v.z, h[2], l[2]); splitbf(v.w, h[3], l[3]);
        *reinterpret_cast<ushort4*>(xh + i) = make_ushort4(h[0], h[1], h[2], h[3]);
        *reinterpret_cast<ushort4*>(xl + i) = make_ushort4(l[0], l[1], l[2], l[3]);
    } else {                                // ---- prep_w (transpose-convert)
        const int pz  = bid - 5120;
        const int zz  = pz >> 8;
        const int rem = pz & 255;
        const float* __restrict__ W = zz == 0 ? Wq : zz == 1 ? Wk : zz == 2 ? Wv : Wo;
        ushort_t* __restrict__ th = wt_hi_base + (size_t)zz * DM * DM * 2;
        ushort_t* __restrict__ tl = wt_lo_base + (size_t)zz * DM * DM * 2;
        const int r0 = (rem >> 4) * 32;     // k rows
        const int c0 = (rem & 15) * 32;     // n cols
        {
            const int r = t >> 3, c4 = (t & 7) * 4;
            float4 v = *reinterpret_cast<const float4*>(W + (size_t)(r0 + r) * DM + c0 + c4);
            Tl[r][c4 + 0] = v.x; Tl[r][c4 + 1] = v.y; Tl[r][c4 + 2] = v.z; Tl[r][c4 + 3] = v.w;
        }
        __syncthreads();
        {
            const int c = t >> 3, r4 = (t & 7) * 4;
            ushort_t h4[4], l4[4];
            #pragma unroll
            for (int k = 0; k < 4; ++k) splitbf(Tl[r4 + k][c], h4[k], l4[k]);
            *reinterpret_cast<ushort4*>(th + (size_t)(c0 + c) * DM + r0 + r4) =
                make_ushort4(h4[0], h4[1], h4[2], h4[3]);
            *reinterpret_cast<ushort4*>(tl + (size_t)(c0 + c) * DM + r0 + r4) =
                make_ushort4(l4[0], l4[1], l4[2], l4[3]);
        }
    }
}

// ----------------------------------------------------------- QKV GEMM ----
// C[2048,512] = x @ W + b via split-bf16 MFMA. Block 64x64, BK=32, 4 waves
// (2x2 of 32x32). z picks Q/K/V. Q,K out: [h][tok][d] hi/lo. V out: [h][d][tok].
__global__ __launch_bounds__(256, 3)
void qkv_gemm_mfma(const ushort_t* __restrict__ x_hi, const ushort_t* __restrict__ x_lo,
                   const ushort_t* __restrict__ wqt_hi, const ushort_t* __restrict__ wqt_lo,
                   const ushort_t* __restrict__ wkt_hi, const ushort_t* __restrict__ wkt_lo,
                   const ushort_t* __restrict__ wvt_hi, const ushort_t* __restrict__ wvt_lo,
                   const float* __restrict__ bq, const float* __restrict__ bk,
                   const float* __restrict__ bv,
                   ushort_t* __restrict__ q_hi, ushort_t* __restrict__ q_lo,
                   ushort_t* __restrict__ k_hi, ushort_t* __restrict__ k_lo,
                   ushort_t* __restrict__ vT_hi, ushort_t* __restrict__ vT_lo) {
    const int z = blockIdx.z;
    const ushort_t* __restrict__ bt_hi = z == 0 ? wqt_hi : z == 1 ? wkt_hi : wvt_hi;
    const ushort_t* __restrict__ bt_lo = z == 0 ? wqt_lo : z == 1 ? wkt_lo : wvt_lo;
    const float*    __restrict__ bias  = z == 0 ? bq : z == 1 ? bk : bv;

    const int n0 = blockIdx.x * 64;
    const int m0 = blockIdx.y * 64;
    const int t  = threadIdx.x;
    const int wid = t >> 6, l = t & 63, hf = l >> 5, lq = l & 31;
    const int wm = wid >> 1, wn = wid & 1;

    __shared__ __align__(16) ushort_t Ash_hi[64 * 40], Ash_lo[64 * 40];
    __shared__ __align__(16) ushort_t Bsh_hi[64 * 40], Bsh_lo[64 * 40];

    f32x16 acc;
    #pragma unroll
    for (int i = 0; i < 16; ++i) acc[i] = 0.0f;

    const int sr = t >> 2, sc = t & 3;   // staging: 64 rows x 4 chunks of 16B

    uint4 ra_h, ra_l, rb_h, rb_l;
    auto LOAD = [&](int k0) {
        ra_h = *reinterpret_cast<const uint4*>(&x_hi[(size_t)(m0 + sr) * DM + k0 + 8 * sc]);
        ra_l = *reinterpret_cast<const uint4*>(&x_lo[(size_t)(m0 + sr) * DM + k0 + 8 * sc]);
        rb_h = *reinterpret_cast<const uint4*>(&bt_hi[(size_t)(n0 + sr) * DM + k0 + 8 * sc]);
        rb_l = *reinterpret_cast<const uint4*>(&bt_lo[(size_t)(n0 + sr) * DM + k0 + 8 * sc]);
    };
    LOAD(0);

    for (int k0 = 0; k0 < DM; k0 += 32) {
        __syncthreads();   // prior compute done reading LDS (WAR)
        *reinterpret_cast<uint4*>(&Ash_hi[sr * 40 + 8 * sc]) = ra_h;
        *reinterpret_cast<uint4*>(&Ash_lo[sr * 40 + 8 * sc]) = ra_l;
        *reinterpret_cast<uint4*>(&Bsh_hi[sr * 40 + 8 * sc]) = rb_h;
        *reinterpret_cast<uint4*>(&Bsh_lo[sr * 40 + 8 * sc]) = rb_l;
        __syncthreads();
        if (k0 + 32 < DM) LOAD(k0 + 32);   // prefetch next tile under compute

        __builtin_amdgcn_s_setprio(1);
        #pragma unroll
        for (int kp = 0; kp < 2; ++kp) {
            const int co = 8 * (hf + 2 * kp);
            short8 ah = *reinterpret_cast<const short8*>(&Ash_hi[(32 * wm + lq) * 40 + co]);
            short8 al = *reinterpret_cast<const short8*>(&Ash_lo[(32 * wm + lq) * 40 + co]);
            short8 bh = *reinterpret_cast<const short8*>(&Bsh_hi[(32 * wn + lq) * 40 + co]);
            short8 bl = *reinterpret_cast<const short8*>(&Bsh_lo[(32 * wn + lq) * 40 + co]);
            acc = MFMA32(ah, bh, acc);
            acc = MFMA32(ah, bl, acc);
            acc = MFMA32(al, bh, acc);
        }
        __builtin_amdgcn_s_setprio(0);
    }

    const int nl = lq + 32 * wn;
    const float bval = bias[n0 + nl];
    const int hh = n0 >> 6;

    #pragma unroll
    for (int r = 0; r < 16; ++r) {
        const int ml = (r & 3) + 8 * (r >> 2) + 4 * hf + 32 * wm;
        const float v = acc[r] + bval;
        ushort_t hi, lo; splitbf(v, hi, lo);
        if (z < 2) {
            ushort_t* dh = z == 0 ? q_hi : k_hi;
            ushort_t* dl = z == 0 ? q_lo : k_lo;
            const size_t o = ((size_t)hh * NTOK + m0 + ml) * DH + nl;
            dh[o] = hi; dl[o] = lo;
        } else {
            const size_t o = ((size_t)hh * DH + nl) * NTOK + m0 + ml;
            vT_hi[o] = hi; vT_lo[o] = lo;
        }
    }
}

// ------------------------------------------------------------ Wo GEMM ----
__global__ __launch_bounds__(256, 3)
void wo_gemm_mfma(const ushort_t* __restrict__ a_hi, const ushort_t* __restrict__ a_lo,
                  const ushort_t* __restrict__ bt_hi, const ushort_t* __restrict__ bt_lo,
                  const float* __restrict__ bias, float* __restrict__ out) {
    const int n0 = blockIdx.x * 64;
    const int m0 = blockIdx.y * 64;
    const int t  = threadIdx.x;
    const int wid = t >> 6, l = t & 63, hf = l >> 5, lq = l & 31;
    const int wm = wid >> 1, wn = wid & 1;

    __shared__ __align__(16) ushort_t Ash_hi[64 * 40], Ash_lo[64 * 40];
    __shared__ __align__(16) ushort_t Bsh_hi[64 * 40], Bsh_lo[64 * 40];

    f32x16 acc;
    #pragma unroll
    for (int i = 0; i < 16; ++i) acc[i] = 0.0f;

    const int sr = t >> 2, sc = t & 3;

    uint4 ra_h, ra_l, rb_h, rb_l;
    auto LOAD = [&](int k0) {
        ra_h = *reinterpret_cast<const uint4*>(&a_hi[(size_t)(m0 + sr) * DM + k0 + 8 * sc]);
        ra_l = *reinterpret_cast<const uint4*>(&a_lo[(size_t)(m0 + sr) * DM + k0 + 8 * sc]);
        rb_h = *reinterpret_cast<const uint4*>(&bt_hi[(size_t)(n0 + sr) * DM + k0 + 8 * sc]);
        rb_l = *reinterpret_cast<const uint4*>(&bt_lo[(size_t)(n0 + sr) * DM + k0 + 8 * sc]);
    };
    LOAD(0);

    for (int k0 = 0; k0 < DM; k0 += 32) {
        __syncthreads();
        *reinterpret_cast<uint4*>(&Ash_hi[sr * 40 + 8 * sc]) = ra_h;
        *reinterpret_cast<uint4*>(&Ash_lo[sr * 40 + 8 * sc]) = ra_l;
        *reinterpret_cast<uint4*>(&Bsh_hi[sr * 40 + 8 * sc]) = rb_h;
        *reinterpret_cast<uint4*>(&Bsh_lo[sr * 40 + 8 * sc]) = rb_l;
        __syncthreads();
        if (k0 + 32 < DM) LOAD(k0 + 32);

        __builtin_amdgcn_s_setprio(1);
        #pragma unroll
        for (int kp = 0; kp < 2; ++kp) {
            const int co = 8 * (hf + 2 * kp);
            short8 ah = *reinterpret_cast<const short8*>(&Ash_hi[(32 * wm + lq) * 40 + co]);
            short8 al = *reinterpret_cast<const short8*>(&Ash_lo[(32 * wm + lq) * 40 + co]);
            short8 bh = *reinterpret_cast<const short8*>(&Bsh_hi[(32 * wn + lq) * 40 + co]);
            short8 bl = *reinterpret_cast<const short8*>(&Bsh_lo[(32 * wn + lq) * 40 + co]);
            acc = MFMA32(ah, bh, acc);
            acc = MFMA32(ah, bl, acc);
            acc = MFMA32(al, bh, acc);
        }
        __builtin_amdgcn_s_setprio(0);
    }

    const int nl = lq + 32 * wn;
    const float bval = bias[n0 + nl];
    #pragma unroll
    for (int r = 0; r < 16; ++r) {
        const int ml = (r & 3) + 8 * (r >> 2) + 4 * hf + 32 * wm;
        out[(size_t)(m0 + ml) * DM + n0 + nl] = acc[r] + bval;
    }
}

// ----------------------------------------------------------- attention ----
// grid (16 qtiles, 8 heads, NSPLIT). QT=128 (4 waves x 32-q strips), KT=64.
// S^T = K·Q^T so each lane owns one q-row: in-register softmax. P split to
// bf16 hi/lo in-register; lane^32 exchange builds PV A-frags.
// Staging: DIRECT global->LDS (R5 form — reg-prefetch here spilled, R7).
__global__ __launch_bounds__(256, 2)
void attn_mfma(const ushort_t* __restrict__ q_hi, const ushort_t* __restrict__ q_lo,
               const ushort_t* __restrict__ k_hi, const ushort_t* __restrict__ k_lo,
               const ushort_t* __restrict__ vT_hi, const ushort_t* __restrict__ vT_lo,
               const unsigned char* __restrict__ bins_g, const float* __restrict__ z_table,
               float* __restrict__ po, float* __restrict__ pm, float* __restrict__ pl) {
    const int hd = blockIdx.y;
    const int q0 = blockIdx.x * 128;
    const int zs = blockIdx.z;
    const int t  = threadIdx.x;
    const int wid = t >> 6, l = t & 63, hf = l >> 5, lq = l & 31;
    const int qs = q0 + 32 * wid;

    __shared__ __align__(16) ushort_t Ksh_hi[64 * 72], Ksh_lo[64 * 72];
    __shared__ __align__(16) ushort_t Vsh_hi[64 * 72], Vsh_lo[64 * 72];
    __shared__ __align__(16) unsigned char Bsh[128 * 80];

    const float ztab = z_table[(l & 15) * NH + hd];

    // Q B-frags in registers
    short8 qf_hi[4], qf_lo[4];
    #pragma unroll
    for (int kp = 0; kp < 4; ++kp) {
        const size_t o = ((size_t)hd * NTOK + qs + lq) * DH + 8 * hf + 16 * kp;
        qf_hi[kp] = *reinterpret_cast<const short8*>(&q_hi[o]);
        qf_lo[kp] = *reinterpret_cast<const short8*>(&q_lo[o]);
    }

    float m_run = -1e30f, l_run = 0.0f;
    f32x16 oacc0, oacc1;
    #pragma unroll
    for (int i = 0; i < 16; ++i) { oacc0[i] = 0.0f; oacc1[i] = 0.0f; }

    const float scale = 0.125f;
    const int kbase = zs * KPS;

    for (int kt8 = 0; kt8 < KPS / 64; ++kt8) {
        const int ktb = kbase + kt8 * 64;
        __syncthreads();   // prior compute done reading LDS (WAR)
        // -- stage K, V^T (hi/lo), bins: direct global->LDS
        #pragma unroll
        for (int i = 0; i < 2; ++i) {
            const int idx = t + 256 * i;
            const int r = idx >> 3, c = idx & 7;
            const size_t kg = ((size_t)hd * NTOK + ktb + r) * DH + 8 * c;
            const size_t vg = ((size_t)hd * DH + r) * NTOK + ktb + 8 * c;
            *reinterpret_cast<uint4*>(&Ksh_hi[r * 72 + 8 * c]) =
                *reinterpret_cast<const uint4*>(&k_hi[kg]);
            *reinterpret_cast<uint4*>(&Ksh_lo[r * 72 + 8 * c]) =
                *reinterpret_cast<const uint4*>(&k_lo[kg]);
            *reinterpret_cast<uint4*>(&Vsh_hi[r * 72 + 8 * c]) =
                *reinterpret_cast<const uint4*>(&vT_hi[vg]);
            *reinterpret_cast<uint4*>(&Vsh_lo[r * 72 + 8 * c]) =
                *reinterpret_cast<const uint4*>(&vT_lo[vg]);
        }
        #pragma unroll
        for (int i = 0; i < 2; ++i) {
            const int idx = t + 256 * i;
            const int qr = idx >> 2, c = idx & 3;
            *reinterpret_cast<uint4*>(&Bsh[qr * 80 + 16 * c]) =
                *reinterpret_cast<const uint4*>(&bins_g[(size_t)(q0 + qr) * NTOK + ktb + 16 * c]);
        }
        __syncthreads();

        // -- S^T = K · Q^T
        f32x16 sacc0, sacc1;
        #pragma unroll
        for (int i = 0; i < 16; ++i) { sacc0[i] = 0.0f; sacc1[i] = 0.0f; }
        __builtin_amdgcn_s_setprio(1);
        #pragma unroll
        for (int kp = 0; kp < 4; ++kp) {
            const int co = 8 * (hf + 2 * kp);
            short8 k0h = *reinterpret_cast<const short8*>(&Ksh_hi[lq * 72 + co]);
            short8 k0l = *reinterpret_cast<const short8*>(&Ksh_lo[lq * 72 + co]);
            short8 k1h = *reinterpret_cast<const short8*>(&Ksh_hi[(lq + 32) * 72 + co]);
            short8 k1l = *reinterpret_cast<const short8*>(&Ksh_lo[(lq + 32) * 72 + co]);
            sacc0 = MFMA32(k0h, qf_hi[kp], sacc0);
            sacc0 = MFMA32(k0h, qf_lo[kp], sacc0);
            sacc0 = MFMA32(k0l, qf_hi[kp], sacc0);
            sacc1 = MFMA32(k1h, qf_hi[kp], sacc1);
            sacc1 = MFMA32(k1h, qf_lo[kp], sacc1);
            sacc1 = MFMA32(k1l, qf_hi[kp], sacc1);
        }
        __builtin_amdgcn_s_setprio(0);

        // -- scale + z-bias
        float sv[2][16];
        #pragma unroll
        for (int t2 = 0; t2 < 2; ++t2) {
            #pragma unroll
            for (int b = 0; b < 4; ++b) {
                const unsigned bw = *reinterpret_cast<const unsigned*>(
                    &Bsh[(32 * wid + lq) * 80 + 4 * (hf + 2 * b + 8 * t2)]);
                #pragma unroll
                for (int c = 0; c < 4; ++c) {
                    const int r = c + 4 * b;
                    const int src = (int)((bw >> (8 * c)) & 0xFF) | (l & 48);
                    const float bias = __shfl(ztab, src, 64);
                    const float sraw = (t2 == 0 ? sacc0[r] : sacc1[r]);
                    sv[t2][r] = sraw * scale + bias;
                }
            }
        }

        // -- online softmax (row spread across lane pair l, l^32)
        float tm = sv[0][0];
        #pragma unroll
        for (int t2 = 0; t2 < 2; ++t2)
            #pragma unroll
            for (int r = 0; r < 16; ++r) tm = fmaxf(tm, sv[t2][r]);
        tm = fmaxf(tm, __shfl_xor(tm, 32, 64));
        const float mn = fmaxf(m_run, tm);
        const float ef = __expf(m_run - mn);
        m_run = mn;

        float pv[2][16];
        float ts = 0.0f;
        #pragma unroll
        for (int t2 = 0; t2 < 2; ++t2)
            #pragma unroll
            for (int r = 0; r < 16; ++r) {
                const float p = __expf(sv[t2][r] - mn);
                pv[t2][r] = p;
                ts += p;
            }
        ts += __shfl_xor(ts, 32, 64);
        l_run = l_run * ef + ts;

        // -- rescale O accumulators
        #pragma unroll
        for (int r = 0; r < 16; ++r) {
            const int qloc = (r & 3) + 8 * (r >> 2) + 4 * hf;
            const float efr = __shfl(ef, qloc | (l & 32), 64);
            oacc0[r] *= efr;
            oacc1[r] *= efr;
        }

        // -- pack P to bf16 hi/lo (native cvt) and build PV A-frags
        unsigned phi[2][8], plo[2][8];
        #pragma unroll
        for (int t2 = 0; t2 < 2; ++t2)
            #pragma unroll
            for (int i = 0; i < 8; ++i) {
                ushort_t ha, la, hb, lb;
                splitbf(pv[t2][2 * i],     ha, la);
                splitbf(pv[t2][2 * i + 1], hb, lb);
                phi[t2][i] = (unsigned)ha | ((unsigned)hb << 16);
                plo[t2][i] = (unsigned)la | ((unsigned)lb << 16);
            }

        FragU paf_hi[2][2], paf_lo[2][2];
        #pragma unroll
        for (int t2 = 0; t2 < 2; ++t2)
            #pragma unroll
            for (int e = 0; e < 2; ++e) {
                {
                    const unsigned pA0 = phi[t2][4 * e], pA1 = phi[t2][4 * e + 1];
                    const unsigned pB0 = phi[t2][4 * e + 2], pB1 = phi[t2][4 * e + 3];
                    const unsigned s0 = hf ? pA0 : pB0, s1 = hf ? pA1 : pB1;
                    const unsigned r0 = (unsigned)__shfl_xor((int)s0, 32, 64);
                    const unsigned r1 = (unsigned)__shfl_xor((int)s1, 32, 64);
                    paf_hi[t2][e].u[0] = hf ? r0 : pA0;
                    paf_hi[t2][e].u[1] = hf ? r1 : pA1;
                    paf_hi[t2][e].u[2] = hf ? pB0 : r0;
                    paf_hi[t2][e].u[3] = hf ? pB1 : r1;
                }
                {
                    const unsigned pA0 = plo[t2][4 * e], pA1 = plo[t2][4 * e + 1];
                    const unsigned pB0 = plo[t2][4 * e + 2], pB1 = plo[t2][4 * e + 3];
                    const unsigned s0 = hf ? pA0 : pB0, s1 = hf ? pA1 : pB1;
                    const unsigned r0 = (unsigned)__shfl_xor((int)s0, 32, 64);
                    const unsigned r1 = (unsigned)__shfl_xor((int)s1, 32, 64);
                    paf_lo[t2][e].u[0] = hf ? r0 : pA0;
                    paf_lo[t2][e].u[1] = hf ? r1 : pA1;
                    paf_lo[t2][e].u[2] = hf ? pB0 : r0;
                    paf_lo[t2][e].u[3] = hf ? pB1 : r1;
                }
            }

        // -- O += P · V
        __builtin_amdgcn_s_setprio(1);
        #pragma unroll
        for (int kp = 0; kp < 4; ++kp) {
            const int t2 = kp >> 1, e = kp & 1;
            const int co = 8 * (hf + 2 * kp);
            short8 v0h = *reinterpret_cast<const short8*>(&Vsh_hi[lq * 72 + co]);
            short8 v0l = *reinterpret_cast<const short8*>(&Vsh_lo[lq * 72 + co]);
            oacc0 = MFMA32(paf_hi[t2][e].s, v0h, oacc0);
            oacc0 = MFMA32(paf_hi[t2][e].s, v0l, oacc0);
            oacc0 = MFMA32(paf_lo[t2][e].s, v0h, oacc0);
            short8 v1h = *reinterpret_cast<const short8*>(&Vsh_hi[(lq + 32) * 72 + co]);
            short8 v1l = *reinterpret_cast<const short8*>(&Vsh_lo[(lq + 32) * 72 + co]);
            oacc1 = MFMA32(paf_hi[t2][e].s, v1h, oacc1);
            oacc1 = MFMA32(paf_hi[t2][e].s, v1l, oacc1);
            oacc1 = MFMA32(paf_lo[t2][e].s, v1h, oacc1);
        }
        __builtin_amdgcn_s_setprio(0);
    }

    // -- epilogue: unnormalized partial O + (m, l)
    #pragma unroll
    for (int r = 0; r < 16; ++r) {
        const int qloc = (r & 3) + 8 * (r >> 2) + 4 * hf;
        const size_t row = ((size_t)(zs * NH + hd) * NTOK + qs + qloc) * DH;
        po[row + lq]      = oacc0[r];
        po[row + lq + 32] = oacc1[r];
    }
    if (hf == 0) {
        const size_t row = (size_t)(zs * NH + hd) * NTOK + qs + lq;
        pm[row] = m_run;
        pl[row] = l_run;
    }
}

// --------------------------------------------------------------- merge ----
__global__ __launch_bounds__(256)
void merge_kernel(const float* __restrict__ po, const float* __restrict__ pm,
                  const float* __restrict__ pl,
                  ushort_t* __restrict__ o_hi, ushort_t* __restrict__ o_lo) {
    const int idx = blockIdx.x * 256 + threadIdx.x;
    const int d4 = (idx & 15) * 4;
    const int q  = (idx >> 4) & (NTOK - 1);
    const int hh = idx >> 15;

    float ms[NSPLIT];
    float M = -1e30f;
    #pragma unroll
    for (int s = 0; s < NSPLIT; ++s) {
        ms[s] = pm[((size_t)s * NH + hh) * NTOK + q];
        M = fmaxf(M, ms[s]);
    }
    float L = 0.0f;
    float4 o = make_float4(0.f, 0.f, 0.f, 0.f);
    #pragma unroll
    for (int s = 0; s < NSPLIT; ++s) {
        const float w = __expf(ms[s] - M);
        L += w * pl[((size_t)s * NH + hh) * NTOK + q];
        float4 p = *reinterpret_cast<const float4*>(
            po + (((size_t)s * NH + hh) * NTOK + q) * DH + d4);
        o.x += w * p.x; o.y += w * p.y; o.z += w * p.z; o.w += w * p.w;
    }
    const float inv = 1.0f / L;
    o.x *= inv; o.y *= inv; o.z *= inv; o.w *= inv;

    ushort_t h4[4], l4[4];
    splitbf(o.x, h4[0], l4[0]); splitbf(o.y, h4[1], l4[1]);
    splitbf(o.z, h4[2], l4[2]); splitbf(o.w, h4[3], l4[3]);
    const size_t oo = (size_t)q * DM + hh * DH + d4;
    *reinterpret_cast<ushort4*>(o_hi + oo) = make_ushort4(h4[0], h4[1], h4[2], h4[3]);
    *reinterpret_cast<ushort4*>(o_lo + oo) = make_ushort4(l4[0], l4[1], l4[2], l4[3]);
}

// --------------------------------------------------------------- launch ----
extern "C" void kernel_launch(void* const* d_in, const int* in_sizes, int n_in,
                              void* d_out, int out_size, void* d_ws, size_t ws_size,
                              hipStream_t stream) {
    const float* x        = (const float*)d_in[0];
    const float* z_matrix = (const float*)d_in[1];
    const float* Wq       = (const float*)d_in[2];
    const float* bq       = (const float*)d_in[3];
    const float* Wk       = (const float*)d_in[4];
    const float* bk       = (const float*)d_in[5];
    const float* Wv       = (const float*)d_in[6];
    const float* bv       = (const float*)d_in[7];
    const float* Wo       = (const float*)d_in[8];
    const float* bo       = (const float*)d_in[9];
    const float* z_table  = (const float*)d_in[10];
    float* out            = (float*)d_out;

    // ---- workspace layout (40.5 MB) ----
    uint8_t* w = (uint8_t*)d_ws;
    const size_t MB = 1024 * 1024;
    ushort_t* x_hi  = (ushort_t*)(w + 0);
    ushort_t* x_lo  = (ushort_t*)(w + 2  * MB);
    ushort_t* wqt_hi= (ushort_t*)(w + 4  * MB);
    ushort_t* wqt_lo= (ushort_t*)(w + 4  * MB + 512 * 1024);
    ushort_t* wkt_hi= (ushort_t*)(w + 5  * MB);
    ushort_t* wkt_lo= (ushort_t*)(w + 5  * MB + 512 * 1024);
    ushort_t* wvt_hi= (ushort_t*)(w + 6  * MB);
    ushort_t* wvt_lo= (ushort_t*)(w + 6  * MB + 512 * 1024);
    ushort_t* wot_hi= (ushort_t*)(w + 7  * MB);
    ushort_t* wot_lo= (ushort_t*)(w + 7  * MB + 512 * 1024);
    ushort_t* q_hi  = (ushort_t*)(w + 8  * MB);
    ushort_t* q_lo  = (ushort_t*)(w + 10 * MB);
    ushort_t* k_hi  = (ushort_t*)(w + 12 * MB);
    ushort_t* k_lo  = (ushort_t*)(w + 14 * MB);
    ushort_t* vT_hi = (ushort_t*)(w + 16 * MB);
    ushort_t* vT_lo = (ushort_t*)(w + 18 * MB);
    unsigned char* bins = (unsigned char*)(w + 20 * MB);
    float* po = (float*)(w + 24 * MB);
    float* pm = (float*)(w + 40 * MB);
    float* pl = (float*)(w + 40 * MB + 256 * 1024);
    ushort_t* o_hi = x_hi;   // alias: x dead after qkv
    ushort_t* o_lo = x_lo;

    // 1) fused prep: bins + conv_x + prep_w
    prep_all<<<dim3(4096 + 1024 + 1024), dim3(256), 0, stream>>>(
        z_matrix, bins, x, x_hi, x_lo, Wq, Wk, Wv, Wo,
        (ushort_t*)(w + 4 * MB), (ushort_t*)(w + 4 * MB + 512 * 1024));

    // 2) QKV projection (z-fused, 768 blocks)
    qkv_gemm_mfma<<<dim3(DM / 64, NTOK / 64, 3), dim3(256), 0, stream>>>(
        x_hi, x_lo,
        wqt_hi, wqt_lo, wkt_hi, wkt_lo, wvt_hi, wvt_lo,
        bq, bk, bv,
        q_hi, q_lo, k_hi, k_lo, vT_hi, vT_lo);

    // 3) attention (512 blocks)
    attn_mfma<<<dim3(NTOK / 128, NH, NSPLIT), dim3(256), 0, stream>>>(
        q_hi, q_lo, k_hi, k_lo, vT_hi, vT_lo, bins, z_table, po, pm, pl);

    // 4) merge partials -> o hi/lo
    merge_kernel<<<dim3(NH * NTOK * DH / 4 / 256), dim3(256), 0, stream>>>(
        po, pm, pl, o_hi, o_lo);

    // 5) output projection
    wo_gemm_mfma<<<dim3(DM / 64, NTOK / 64), dim3(256), 0, stream>>>(
        o_hi, o_lo, wot_hi, wot_lo, bo, out);
}